// Round 6
// baseline (58.831 us; speedup 1.0000x reference)
//
#include <hip/hip_runtime.h>

typedef float f4 __attribute__((ext_vector_type(4)));

// Problem constants: B=8, N=8192, K=16, C_in=C_out=64
#define BB 8
#define NN 8192
#define KK 16
#define CC 64
#define TPB 64                   // tokens per chunk
#define THREADS 256
#define CPB (NN / TPB)           // 128 chunks per batch
#define NCHUNK (BB * CPB)        // 1024
#define NTOK (BB * NN)
#define BN_EPS 1e-5f

// K1: KNN-gather-mean in x-space + projection + BN partials.
// Work assignment is DYNAMIC: each block reads its physical XCD (XCC_ID) and
// claims a chunk of the batch pinned to that XCD via atomic tickets. This
// guarantees batch<->XCD affinity regardless of the dispatcher's block->XCD
// mapping (which is undefined), keeping each XCD's gather working set at
// x-slice (2MB) + knn (0.5MB) < 4MB L2.
__global__ __launch_bounds__(THREADS, 4) void k_main(
    const float* __restrict__ x, const int* __restrict__ knn,
    const float* __restrict__ W, float* __restrict__ out,
    float* __restrict__ partials, int* __restrict__ tickets)
{
    __shared__ float sWt[CC][CC];                         // W^T: sWt[c][o], 16KB
    __shared__ union { float agg[TPB][CC + 4]; float red[2][16][CC]; } u;
    __shared__ int sChunk;

    const int tid = threadIdx.x;

    if (tid == 0) {
        unsigned int xcc;
        asm volatile("s_getreg_b32 %0, hwreg(HW_REG_XCC_ID)" : "=s"(xcc));
        xcc &= 7;
        int got = -1;
        // Try own-XCD batch first, then spill to others. Total tickets ==
        // total blocks, and a counter only rejects once its 128 chunks are
        // claimed, so every block finds exactly one chunk (proof: all-full
        // would mean 1024 chunks claimed by the other 1023 blocks).
        #pragma unroll
        for (int a = 0; a < 8; ++a) {
            const int bb = (xcc + a) & 7;
            if (got < 0) {
                const int t = atomicAdd(&tickets[bb], 1);
                if (t < CPB) got = bb * CPB + t;
            }
        }
        sChunk = got;
    }
    for (int i = tid; i < CC * CC; i += THREADS)          // overlaps the ticketing
        sWt[i & 63][i >> 6] = W[i];
    __syncthreads();

    const int ch    = sChunk;
    const int batch = ch >> 7;
    const int nb    = (ch & (CPB - 1)) * TPB;

    // ---- Phase A: gather-mean. 16 lanes per token; lane l owns channels 4l..4l+3.
    const int g = tid >> 4, l = tid & 15;
    const f4* __restrict__ x4b = (const f4*)x + (size_t)batch * NN * (CC / 4);

    for (int it = 0; it < 4; ++it) {
        const int t = it * 16 + g;
        const int idx_my =
            __builtin_nontemporal_load(&knn[(batch * NN + nb + t) * KK + l]);
        int idxs[16];
        #pragma unroll
        for (int k = 0; k < KK; ++k) idxs[k] = __shfl(idx_my, k, 16);
        f4 v[16];
        #pragma unroll
        for (int k = 0; k < KK; ++k) v[k] = x4b[idxs[k] * (CC / 4) + l];
        #pragma unroll
        for (int s = 8; s; s >>= 1)
            #pragma unroll
            for (int k = 0; k < s; ++k) v[k] += v[k + s];
        *(f4*)&u.agg[t][l * 4] = v[0] * (1.0f / KK);
    }
    __syncthreads();

    // ---- Phase B: projection. Thread (tq,oq) owns tokens tq*4..+3, outputs oq*4..+3.
    const int tq = tid >> 4, oq = tid & 15;
    float acc[4][4] = {};
    #pragma unroll
    for (int c4 = 0; c4 < CC; c4 += 4) {
        float av[4][4], wv[4][4];
        #pragma unroll
        for (int t = 0; t < 4; ++t) {
            const f4 tmp = *(const f4*)&u.agg[tq * 4 + t][c4];
            av[t][0] = tmp.x; av[t][1] = tmp.y; av[t][2] = tmp.z; av[t][3] = tmp.w;
        }
        #pragma unroll
        for (int cc = 0; cc < 4; ++cc) {
            const f4 tmp = *(const f4*)&sWt[c4 + cc][oq * 4];
            wv[cc][0] = tmp.x; wv[cc][1] = tmp.y; wv[cc][2] = tmp.z; wv[cc][3] = tmp.w;
        }
        #pragma unroll
        for (int t = 0; t < 4; ++t)
            #pragma unroll
            for (int cc = 0; cc < 4; ++cc)
                #pragma unroll
                for (int o = 0; o < 4; ++o)
                    acc[t][o] += av[t][cc] * wv[cc][o];
    }

    // ---- Write agg (into d_out) — non-temporal: protect L2 x-slice residency
    f4* __restrict__ out4 = (f4*)out;
    #pragma unroll
    for (int t = 0; t < 4; ++t) {
        f4 r; r.x = acc[t][0]; r.y = acc[t][1]; r.z = acc[t][2]; r.w = acc[t][3];
        __builtin_nontemporal_store(
            r, &out4[(size_t)(batch * NN + nb + tq * 4 + t) * (CC / 4) + oq]);
    }

    // ---- Per-chunk BN partials (coalesced: partials[chunk][128])
    __syncthreads();   // before overwriting u.agg with u.red
    float ps[4] = {}, pq[4] = {};
    #pragma unroll
    for (int t = 0; t < 4; ++t)
        #pragma unroll
        for (int o = 0; o < 4; ++o) {
            ps[o] += acc[t][o];
            pq[o] += acc[t][o] * acc[t][o];
        }
    #pragma unroll
    for (int o = 0; o < 4; ++o) {
        u.red[0][tq][oq * 4 + o] = ps[o];
        u.red[1][tq][oq * 4 + o] = pq[o];
    }
    __syncthreads();
    if (tid < 128) {                       // 0..63 = sum(c), 64..127 = sumsq(c)
        const int w = tid >> 6, c = tid & 63;
        float s = 0.f;
        #pragma unroll
        for (int i = 0; i < 16; ++i) s += u.red[w][i][c];
        partials[(size_t)ch * 128 + tid] = s;
    }
}

// K2: finalize BN stats -> ss[0..63]=scale, ss[64..127]=shift
__global__ __launch_bounds__(THREADS) void k_stats(
    const float* __restrict__ partials, const float* __restrict__ gamma,
    const float* __restrict__ beta, float* __restrict__ ss)
{
    __shared__ float sFin[8];
    const int tid = threadIdx.x;
    const int j = blockIdx.x;            // channel 0..63
    float s1 = 0.f, s2 = 0.f;
    for (int i = tid; i < NCHUNK; i += THREADS) {
        s1 += partials[(size_t)i * 128 + j];
        s2 += partials[(size_t)i * 128 + 64 + j];
    }
    #pragma unroll
    for (int off = 32; off; off >>= 1) {
        s1 += __shfl_down(s1, off);
        s2 += __shfl_down(s2, off);
    }
    if ((tid & 63) == 0) { sFin[tid >> 6] = s1; sFin[4 + (tid >> 6)] = s2; }
    __syncthreads();
    if (tid == 0) {
        const float S1 = sFin[0] + sFin[1] + sFin[2] + sFin[3];
        const float S2 = sFin[4] + sFin[5] + sFin[6] + sFin[7];
        const float invn = 1.0f / (float)NTOK;
        const float mu  = S1 * invn;
        const float var = S2 * invn - mu * mu;
        const float sc  = gamma[j] * rsqrtf(var + BN_EPS);
        ss[j]      = sc;
        ss[CC + j] = beta[j] - mu * sc;
    }
}

// K3: in-place normalize d_out: out = agg*scale[c] + shift[c]  (32MB stream)
__global__ __launch_bounds__(256) void k_norm(
    float* __restrict__ out, const float* __restrict__ ss)
{
    const int idx = blockIdx.x * 256 + threadIdx.x;   // f4 index
    f4* out4 = (f4*)out;
    const f4 a  = out4[idx];
    const int c4 = idx & (CC / 4 - 1);
    const f4 sc = ((const f4*)ss)[c4];
    const f4 sh = ((const f4*)ss)[CC / 4 + c4];
    f4 r;
    r.x = fmaf(a.x, sc.x, sh.x);
    r.y = fmaf(a.y, sc.y, sh.y);
    r.z = fmaf(a.z, sc.z, sh.z);
    r.w = fmaf(a.w, sc.w, sh.w);
    __builtin_nontemporal_store(r, &out4[idx]);
}

extern "C" void kernel_launch(void* const* d_in, const int* in_sizes, int n_in,
                              void* d_out, int out_size, void* d_ws, size_t ws_size,
                              hipStream_t stream)
{
    const float* x     = (const float*)d_in[0];
    const int*   knn   = (const int*)d_in[1];
    const float* W     = (const float*)d_in[2];
    const float* gamma = (const float*)d_in[3];
    const float* beta  = (const float*)d_in[4];
    float* out = (float*)d_out;

    float* partials = (float*)d_ws;              // 1024*128 floats
    float* ss       = partials + NCHUNK * 128;   // 128 floats
    int*   tickets  = (int*)(ss + 128);          // 8 ints, must be zeroed per call

    hipMemsetAsync(tickets, 0, 8 * sizeof(int), stream);
    k_main <<<NCHUNK, THREADS, 0, stream>>>(x, knn, W, out, partials, tickets);
    k_stats<<<64, THREADS, 0, stream>>>(partials, gamma, beta, ss);
    k_norm <<<(NTOK * CC) / 4 / 256, 256, 0, stream>>>(out, ss);
}

// Round 7
// 45.050 us; speedup vs baseline: 1.3059x; 1.3059x over previous
//
#include <hip/hip_runtime.h>
#include <hip/hip_fp16.h>

typedef float f4 __attribute__((ext_vector_type(4)));

// Problem constants: B=8, N=8192, K=16, C_in=C_out=64
#define BB 8
#define NN 8192
#define KK 16
#define CC 64
#define TPB 64                   // tokens per chunk/block in k_main
#define THREADS 256
#define NCHUNK 1024              // 8 batches * 128 chunks
#define NTOK (BB * NN)
#define BN_EPS 1e-5f

// K0: pack x fp32 -> fp16 (halves the gather's cache-line count: 256B->128B rows)
__global__ __launch_bounds__(256) void k_pack(
    const float* __restrict__ x, __half2* __restrict__ x16)
{
    const int i = blockIdx.x * 256 + threadIdx.x;      // one f4 -> two half2
    const f4 v = ((const f4*)x)[i];
    x16[2 * i]     = __floats2half2_rn(v.x, v.y);
    x16[2 * i + 1] = __floats2half2_rn(v.z, v.w);
}

// K1 (fp16 gather): KNN-gather-mean in x16-space + projection + BN partials.
// Lane l owns channels 4l..4l+3 = one uint2 (8B) of the 128B fp16 row.
__global__ __launch_bounds__(THREADS, 4) void k_main16(
    const __half2* __restrict__ x16, const int* __restrict__ knn,
    const float* __restrict__ W, float* __restrict__ out,
    float* __restrict__ partials)
{
    __shared__ float sWt[CC][CC];                         // W^T: sWt[c][o], 16KB
    __shared__ union { float agg[TPB][CC + 4]; float red[2][16][CC]; } u;

    const int tid   = threadIdx.x;
    const int batch = blockIdx.x & 7;
    const int nb    = (blockIdx.x >> 3) * TPB;

    for (int i = tid; i < CC * CC; i += THREADS)
        sWt[i & 63][i >> 6] = W[i];

    // ---- Phase A: gather-mean (fp16 rows, 2 lines/row)
    const int g = tid >> 4, l = tid & 15;
    const uint2* __restrict__ xr =
        (const uint2*)x16 + (size_t)batch * NN * 16;      // row = 16 uint2

    for (int it = 0; it < 4; ++it) {
        const int t = it * 16 + g;
        const int idx_my =
            __builtin_nontemporal_load(&knn[(batch * NN + nb + t) * KK + l]);
        int idxs[16];
        #pragma unroll
        for (int k = 0; k < KK; ++k) idxs[k] = __shfl(idx_my, k, 16);
        uint2 v[16];
        #pragma unroll
        for (int k = 0; k < KK; ++k) v[k] = xr[(size_t)idxs[k] * 16 + l];
        // packed-half tree sum (sum of 16 N(0,1): well within fp16 range)
        __half2 a[16], b[16];
        #pragma unroll
        for (int k = 0; k < KK; ++k) {
            a[k] = *(const __half2*)&v[k].x;
            b[k] = *(const __half2*)&v[k].y;
        }
        #pragma unroll
        for (int s = 8; s; s >>= 1)
            #pragma unroll
            for (int k = 0; k < s; ++k) { a[k] = __hadd2(a[k], a[k + s]); b[k] = __hadd2(b[k], b[k + s]); }
        const float inv = 1.0f / KK;
        f4 r;
        r.x = __low2float(a[0]) * inv; r.y = __high2float(a[0]) * inv;
        r.z = __low2float(b[0]) * inv; r.w = __high2float(b[0]) * inv;
        *(f4*)&u.agg[t][l * 4] = r;
    }
    __syncthreads();

    // ---- Phase B: projection. Thread (tq,oq): tokens tq*4..+3, outputs oq*4..+3.
    const int tq = tid >> 4, oq = tid & 15;
    float acc[4][4] = {};
    #pragma unroll
    for (int c4 = 0; c4 < CC; c4 += 4) {
        float av[4][4], wv[4][4];
        #pragma unroll
        for (int t = 0; t < 4; ++t) {
            const f4 tmp = *(const f4*)&u.agg[tq * 4 + t][c4];
            av[t][0] = tmp.x; av[t][1] = tmp.y; av[t][2] = tmp.z; av[t][3] = tmp.w;
        }
        #pragma unroll
        for (int cc = 0; cc < 4; ++cc) {
            const f4 tmp = *(const f4*)&sWt[c4 + cc][oq * 4];
            wv[cc][0] = tmp.x; wv[cc][1] = tmp.y; wv[cc][2] = tmp.z; wv[cc][3] = tmp.w;
        }
        #pragma unroll
        for (int t = 0; t < 4; ++t)
            #pragma unroll
            for (int cc = 0; cc < 4; ++cc)
                #pragma unroll
                for (int o = 0; o < 4; ++o)
                    acc[t][o] += av[t][cc] * wv[cc][o];
    }

    // ---- Write h (into d_out), non-temporal
    f4* __restrict__ out4 = (f4*)out;
    #pragma unroll
    for (int t = 0; t < 4; ++t) {
        f4 r; r.x = acc[t][0]; r.y = acc[t][1]; r.z = acc[t][2]; r.w = acc[t][3];
        __builtin_nontemporal_store(
            r, &out4[(size_t)(batch * NN + nb + tq * 4 + t) * (CC / 4) + oq]);
    }

    // ---- Per-chunk BN partials
    __syncthreads();
    float ps[4] = {}, pq[4] = {};
    #pragma unroll
    for (int t = 0; t < 4; ++t)
        #pragma unroll
        for (int o = 0; o < 4; ++o) {
            ps[o] += acc[t][o];
            pq[o] += acc[t][o] * acc[t][o];
        }
    #pragma unroll
    for (int o = 0; o < 4; ++o) {
        u.red[0][tq][oq * 4 + o] = ps[o];
        u.red[1][tq][oq * 4 + o] = pq[o];
    }
    __syncthreads();
    if (tid < 128) {
        const int w = tid >> 6, c = tid & 63;
        float s = 0.f;
        #pragma unroll
        for (int i = 0; i < 16; ++i) s += u.red[w][i][c];
        partials[(size_t)blockIdx.x * 128 + tid] = s;
    }
}

// K1 fallback (fp32 gather) — used only if ws_size can't hold x16
__global__ __launch_bounds__(THREADS, 4) void k_main32(
    const float* __restrict__ x, const int* __restrict__ knn,
    const float* __restrict__ W, float* __restrict__ out,
    float* __restrict__ partials)
{
    __shared__ float sWt[CC][CC];
    __shared__ union { float agg[TPB][CC + 4]; float red[2][16][CC]; } u;
    const int tid   = threadIdx.x;
    const int batch = blockIdx.x & 7;
    const int nb    = (blockIdx.x >> 3) * TPB;
    for (int i = tid; i < CC * CC; i += THREADS) sWt[i & 63][i >> 6] = W[i];
    const int g = tid >> 4, l = tid & 15;
    const f4* __restrict__ x4b = (const f4*)x + (size_t)batch * NN * (CC / 4);
    for (int it = 0; it < 4; ++it) {
        const int t = it * 16 + g;
        const int idx_my =
            __builtin_nontemporal_load(&knn[(batch * NN + nb + t) * KK + l]);
        int idxs[16];
        #pragma unroll
        for (int k = 0; k < KK; ++k) idxs[k] = __shfl(idx_my, k, 16);
        f4 v[16];
        #pragma unroll
        for (int k = 0; k < KK; ++k) v[k] = x4b[idxs[k] * (CC / 4) + l];
        #pragma unroll
        for (int s = 8; s; s >>= 1)
            #pragma unroll
            for (int k = 0; k < s; ++k) v[k] += v[k + s];
        *(f4*)&u.agg[t][l * 4] = v[0] * (1.0f / KK);
    }
    __syncthreads();
    const int tq = tid >> 4, oq = tid & 15;
    float acc[4][4] = {};
    #pragma unroll
    for (int c4 = 0; c4 < CC; c4 += 4) {
        float av[4][4], wv[4][4];
        #pragma unroll
        for (int t = 0; t < 4; ++t) {
            const f4 tmp = *(const f4*)&u.agg[tq * 4 + t][c4];
            av[t][0] = tmp.x; av[t][1] = tmp.y; av[t][2] = tmp.z; av[t][3] = tmp.w;
        }
        #pragma unroll
        for (int cc = 0; cc < 4; ++cc) {
            const f4 tmp = *(const f4*)&sWt[c4 + cc][oq * 4];
            wv[cc][0] = tmp.x; wv[cc][1] = tmp.y; wv[cc][2] = tmp.z; wv[cc][3] = tmp.w;
        }
        #pragma unroll
        for (int t = 0; t < 4; ++t)
            #pragma unroll
            for (int cc = 0; cc < 4; ++cc)
                #pragma unroll
                for (int o = 0; o < 4; ++o)
                    acc[t][o] += av[t][cc] * wv[cc][o];
    }
    f4* __restrict__ out4 = (f4*)out;
    #pragma unroll
    for (int t = 0; t < 4; ++t) {
        f4 r; r.x = acc[t][0]; r.y = acc[t][1]; r.z = acc[t][2]; r.w = acc[t][3];
        __builtin_nontemporal_store(
            r, &out4[(size_t)(batch * NN + nb + tq * 4 + t) * (CC / 4) + oq]);
    }
    __syncthreads();
    float ps[4] = {}, pq[4] = {};
    #pragma unroll
    for (int t = 0; t < 4; ++t)
        #pragma unroll
        for (int o = 0; o < 4; ++o) {
            ps[o] += acc[t][o];
            pq[o] += acc[t][o] * acc[t][o];
        }
    #pragma unroll
    for (int o = 0; o < 4; ++o) {
        u.red[0][tq][oq * 4 + o] = ps[o];
        u.red[1][tq][oq * 4 + o] = pq[o];
    }
    __syncthreads();
    if (tid < 128) {
        const int w = tid >> 6, c = tid & 63;
        float s = 0.f;
        #pragma unroll
        for (int i = 0; i < 16; ++i) s += u.red[w][i][c];
        partials[(size_t)blockIdx.x * 128 + tid] = s;
    }
}

// K2: finalize BN stats -> ss[0..63]=scale, ss[64..127]=shift
__global__ __launch_bounds__(THREADS) void k_stats(
    const float* __restrict__ partials, const float* __restrict__ gamma,
    const float* __restrict__ beta, float* __restrict__ ss)
{
    __shared__ float sFin[8];
    const int tid = threadIdx.x;
    const int j = blockIdx.x;
    float s1 = 0.f, s2 = 0.f;
    for (int i = tid; i < NCHUNK; i += THREADS) {
        s1 += partials[(size_t)i * 128 + j];
        s2 += partials[(size_t)i * 128 + 64 + j];
    }
    #pragma unroll
    for (int off = 32; off; off >>= 1) {
        s1 += __shfl_down(s1, off);
        s2 += __shfl_down(s2, off);
    }
    if ((tid & 63) == 0) { sFin[tid >> 6] = s1; sFin[4 + (tid >> 6)] = s2; }
    __syncthreads();
    if (tid == 0) {
        const float S1 = sFin[0] + sFin[1] + sFin[2] + sFin[3];
        const float S2 = sFin[4] + sFin[5] + sFin[6] + sFin[7];
        const float invn = 1.0f / (float)NTOK;
        const float mu  = S1 * invn;
        const float var = S2 * invn - mu * mu;
        const float sc  = gamma[j] * rsqrtf(var + BN_EPS);
        ss[j]      = sc;
        ss[CC + j] = beta[j] - mu * sc;
    }
}

// K3: in-place normalize d_out
__global__ __launch_bounds__(256) void k_norm(
    float* __restrict__ out, const float* __restrict__ ss)
{
    const int idx = blockIdx.x * 256 + threadIdx.x;
    f4* out4 = (f4*)out;
    const f4 a  = out4[idx];
    const int c4 = idx & (CC / 4 - 1);
    const f4 sc = ((const f4*)ss)[c4];
    const f4 sh = ((const f4*)ss)[CC / 4 + c4];
    f4 r;
    r.x = fmaf(a.x, sc.x, sh.x);
    r.y = fmaf(a.y, sc.y, sh.y);
    r.z = fmaf(a.z, sc.z, sh.z);
    r.w = fmaf(a.w, sc.w, sh.w);
    __builtin_nontemporal_store(r, &out4[idx]);
}

extern "C" void kernel_launch(void* const* d_in, const int* in_sizes, int n_in,
                              void* d_out, int out_size, void* d_ws, size_t ws_size,
                              hipStream_t stream)
{
    const float* x     = (const float*)d_in[0];
    const int*   knn   = (const int*)d_in[1];
    const float* W     = (const float*)d_in[2];
    const float* gamma = (const float*)d_in[3];
    const float* beta  = (const float*)d_in[4];
    float* out = (float*)d_out;

    float*   partials = (float*)d_ws;                     // 1024*128 f32 = 512KB
    float*   ss       = partials + NCHUNK * 128;          // 128 f32
    __half2* x16      = (__half2*)(ss + 128);             // 2.1M half2 = 8MB

    const size_t need = (size_t)(NCHUNK * 128 + 128) * 4 + (size_t)NTOK * CC * 2;

    if (ws_size >= need) {
        k_pack  <<<(NTOK * CC) / 4 / 256, 256, 0, stream>>>(x, x16);
        k_main16<<<NCHUNK, THREADS, 0, stream>>>(x16, knn, W, out, partials);
    } else {
        k_main32<<<NCHUNK, THREADS, 0, stream>>>(x, knn, W, out, partials);
    }
    k_stats<<<64, THREADS, 0, stream>>>(partials, gamma, beta, ss);
    k_norm <<<(NTOK * CC) / 4 / 256, 256, 0, stream>>>(out, ss);
}